// Round 9
// baseline (174.708 us; speedup 1.0000x reference)
//
#include <hip/hip_runtime.h>
#include <math.h>

#define NSITES 131072      // 32*16*16*16
#define PL     (NSITES * 9)   // floats per feature plane

struct cplx { float re, im; };

__device__ __forceinline__ cplx cadd(cplx a, cplx b) { return {a.re + b.re, a.im + b.im}; }
__device__ __forceinline__ cplx cmul(cplx a, cplx b) {
    return { fmaf(a.re, b.re, -(a.im * b.im)), fmaf(a.re, b.im, a.im * b.re) };
}

// 12-byte vector load (global_load_dwordx3); rows are 36 B so only 4B-aligned
struct __attribute__((aligned(4))) f3 { float x, y, z; };
__device__ __forceinline__ f3 ld3(const float* __restrict__ p) { return *(const f3*)p; }
__device__ __forceinline__ void ld9(const float* __restrict__ p, float* r) {
    f3 a = *(const f3*)p, b = *(const f3*)(p + 3), c = *(const f3*)(p + 6);
    r[0] = a.x; r[1] = a.y; r[2] = a.z;
    r[3] = b.x; r[4] = b.y; r[5] = b.z;
    r[6] = c.x; r[7] = c.y; r[8] = c.z;
}

// 8-DOF anti-hermitian traceless E:
//  E = [[i*ed0, er01+i*ei01, er02+i*ei02],
//       [-er01+i*ei01, i*ed1, er12+i*ei12],
//       [-er02+i*ei02, -er12+i*ei12, i*ed2]]
struct Edof { float er01, er02, er12, ei01, ei02, ei12, ed0, ed1, ed2; };

__device__ __forceinline__ Edof make_edof(const float* acc) {
    Edof E;
    E.er01 = acc[0]; E.er02 = acc[1]; E.er12 = acc[2];
    E.ei01 = acc[3]; E.ei02 = acc[4]; E.ei12 = acc[5];
    float t3 = (acc[6] + acc[7] + acc[8]) * (2.f / 3.f);
    E.ed0 = fmaf(2.f, acc[6], -t3);
    E.ed1 = fmaf(2.f, acc[7], -t3);
    E.ed2 = fmaf(2.f, acc[8], -t3);     // == -ed0-ed1
    return E;
}

// exp(E) = g0 I + g1 E + g2 E^2 via Cayley-Hamilton (p real, q imaginary),
// scaling from exponent bits of ||E||_F^2, Taylor(10) + repeated squaring.
__device__ __forceinline__ void expm_coeffs(const Edof& E, cplx& g0o, cplx& g1o, cplx& g2o)
{
    float r2 = fmaf(E.er01, E.er01, fmaf(E.er02, E.er02, fmaf(E.er12, E.er12,
               fmaf(E.ei01, E.ei01, fmaf(E.ei02, E.ei02, E.ei12 * E.ei12)))));
    r2 = fmaf(2.f, r2, fmaf(E.ed0, E.ed0, fmaf(E.ed1, E.ed1, E.ed2 * E.ed2)));

    const float n01 = fmaf(E.ei01, E.ei01, E.er01 * E.er01);
    const float n02 = fmaf(E.ei02, E.ei02, E.er02 * E.er02);
    const float n12 = fmaf(E.ei12, E.ei12, E.er12 * E.er12);
    const float zre = fmaf(E.ei01, E.ei12, -(E.er01 * E.er12));
    const float zim = -fmaf(E.ei01, E.er12, E.er01 * E.ei12);
    const float detH = E.ed0 * E.ed1 * E.ed2
                     + 2.f * fmaf(zre, E.ei02, -(zim * E.er02))
                     - fmaf(E.ed0, n12, fmaf(E.ed1, n02, E.ed2 * n01));

    int e; (void)frexpf(r2, &e);                 // r2 = m*2^e, m in [0.5,1)
    int sc = (e <= -2) ? 0 : min(1 + ((e + 1) >> 1), 40);
    const float inv  = __int_as_float((127 - sc) << 23);   // 2^-sc
    const float inv2 = inv * inv;
    const float px   = -0.5f * r2 * inv2;        // p of scaled X (real)
    const float qxi  = -detH * (inv2 * inv);     // q of scaled X = i*qxi

    cplx T0 = {1.f, 0.f}, T1 = {0.f, 0.f}, T2 = {0.f, 0.f};
    cplx S0 = {1.f, 0.f}, S1 = {0.f, 0.f}, S2 = {0.f, 0.f};
    #pragma unroll
    for (int n = 1; n <= 10; n++) {
        float c  = 1.f / (float)n;               // folds to a literal
        float qc = qxi * c;
        cplx nT0 = { -qc * T2.im, qc * T2.re };
        cplx nT1 = { c * fmaf(px, T2.re, T0.re), c * fmaf(px, T2.im, T0.im) };
        cplx nT2 = { c * T1.re, c * T1.im };
        T0 = nT0; T1 = nT1; T2 = nT2;
        S0 = cadd(S0, T0); S1 = cadd(S1, T1); S2 = cadd(S2, T2);
    }

    const float q2 = 2.f * qxi;
    for (int k = 0; k < sc; k++) {
        cplx f0 = S0, f1 = S1, f2 = S2;
        cplx f12 = cmul(f1, f2);
        cplx f01 = cmul(f0, f1);
        cplx f02 = cmul(f0, f2);
        float f00re = fmaf(f0.re, f0.re, -(f0.im * f0.im)), f00im = 2.f * f0.re * f0.im;
        float f11re = fmaf(f1.re, f1.re, -(f1.im * f1.im)), f11im = 2.f * f1.re * f1.im;
        float f22re = fmaf(f2.re, f2.re, -(f2.im * f2.im)), f22im = 2.f * f2.re * f2.im;
        S0.re = fmaf(-q2, f12.im, f00re);
        S0.im = fmaf( q2, f12.re, f00im);
        S1.re = fmaf(-qxi, f22im, 2.f * fmaf(px, f12.re, f01.re));
        S1.im = fmaf( qxi, f22re, 2.f * fmaf(px, f12.im, f01.im));
        S2.re = fmaf(px, f22re, fmaf(2.f, f02.re, f11re));
        S2.im = fmaf(px, f22im, fmaf(2.f, f02.im, f11im));
    }
    g0o = S0;
    g1o = { S1.re * inv,  S1.im * inv  };
    g2o = { S2.re * inv2, S2.im * inv2 };
}

__device__ __forceinline__ void ecol(const Edof& E, cplx m0, cplx m1, cplx m2,
                                     cplx& v0, cplx& v1, cplx& v2)
{
    v0.re = fmaf(-E.ed0, m0.im, fmaf(E.er01, m1.re, fmaf(-E.ei01, m1.im, fmaf(E.er02, m2.re, -(E.ei02 * m2.im)))));
    v0.im = fmaf( E.ed0, m0.re, fmaf(E.er01, m1.im, fmaf( E.ei01, m1.re, fmaf(E.er02, m2.im,  (E.ei02 * m2.re)))));
    v1.re = fmaf(-E.er01, m0.re, fmaf(-E.ei01, m0.im, fmaf(-E.ed1, m1.im, fmaf(E.er12, m2.re, -(E.ei12 * m2.im)))));
    v1.im = fmaf(-E.er01, m0.im, fmaf( E.ei01, m0.re, fmaf( E.ed1, m1.re, fmaf(E.er12, m2.im,  (E.ei12 * m2.re)))));
    v2.re = fmaf(-E.er02, m0.re, fmaf(-E.ei02, m0.im, fmaf(-E.er12, m1.re, fmaf(-E.ei12, m1.im, -(E.ed2 * m2.im)))));
    v2.im = fmaf(-E.er02, m0.im, fmaf( E.ei02, m0.re, fmaf(-E.er12, m1.im, fmaf( E.ei12, m1.re,  (E.ed2 * m2.re)))));
}

__device__ __forceinline__ float ocomb(cplx g0, cplx g1, cplx g2, cplx m, cplx v, cplx z) {
    return fmaf(g0.re, m.re, fmaf(-g0.im, m.im, fmaf(g1.re, v.re, fmaf(-g1.im, v.im,
           fmaf(g2.re, z.re, -(g2.im * z.im))))));
}

__device__ __forceinline__ void apply_store(const Edof& E, cplx g0, cplx g1, cplx g2,
                                            const float* ur, const float* ui,
                                            float* __restrict__ ob)
{
    float o[9];
    #pragma unroll
    for (int b = 0; b < 3; b++) {
        cplx m0 = { ur[b],     ui[b]     };
        cplx m1 = { ur[3 + b], ui[3 + b] };
        cplx m2 = { ur[6 + b], ui[6 + b] };
        cplx v0, v1, v2, z0, z1, z2;
        ecol(E, m0, m1, m2, v0, v1, v2);   // V col = E * U col
        ecol(E, v0, v1, v2, z0, z1, z2);   // Z col = E * V col
        o[b]     = ocomb(g0, g1, g2, m0, v0, z0);
        o[3 + b] = ocomb(g0, g1, g2, m1, v1, z1);
        o[6 + b] = ocomb(g0, g1, g2, m2, v2, z2);
    }
    *(f3*)(ob)     = { o[0], o[1], o[2] };
    *(f3*)(ob + 3) = { o[3], o[4], o[5] };
    *(f3*)(ob + 6) = { o[6], o[7], o[8] };
}

// ONE LANE = ONE SITE, ALL 4 MU. Lane-byte ceiling model (fits R4/R8): the
// vector memory path services ~6.3-6.8 TB/s of LANE-level bytes (duplicates
// included); R4/R8 serviced ~308 MB (4 mu-lanes x identical 480 B of W per
// site) -> 45 us AT the ceiling. This kernel loads W once per site (480 B),
// pre-reduces to 9 floats, and accumulates all four E's with ahw weights that
// are FULLY UNIFORM -> SGPR operands (s_load), zero redistribution cost (no
// swizzle/LDS -- R5's mistake). Serviced bytes: 308 -> ~120 MB (2.6x cut).
// 2048 waves (8/CU): MLP need is ~1.2 KB in flight per wave -- trivially met.
// VALU per lane x4 but lanes /4: aggregate ~5 us/SIMD, hides under memory.
//
// launch_bounds NOTE (measured): (256,8) 64-VGPR cap -> 155 MB spill;
// (256,6) pressure mode -> 48.7 MB spill; (256,4) = 128-reg budget, clean in
// R0/R3/R4/R5/R8. This kernel needs ~100 VGPR: watch WRITE_SIZE for spill.
__global__ __launch_bounds__(256, 4) void lge_exp_kernel(
    const float* __restrict__ U_re, const float* __restrict__ U_im,
    const float* __restrict__ W_re, const float* __restrict__ W_im,
    const float* __restrict__ ahw,  float* __restrict__ out)
{
    const int site = blockIdx.x * 256 + threadIdx.x;   // 0..131071
    const size_t sb = (size_t)site * 9;

    // ---- E accumulation for ALL 4 mu, one pass over W ----
    // acc layout per mu: {er01, er02, er12, si01, si02, si12, d0, d4, d8}
    float acc0[9] = {0,0,0,0,0,0,0,0,0};
    float acc1[9] = {0,0,0,0,0,0,0,0,0};
    float acc2[9] = {0,0,0,0,0,0,0,0,0};
    float acc3[9] = {0,0,0,0,0,0,0,0,0};

    #pragma unroll
    for (int f = 0; f < 8; f++) {
        const float* pr = W_re + (size_t)f * PL + sb;
        const float* pi = W_im + (size_t)f * PL + sb;
        f3 q = ld3(pr + 1);            // w1 w2 w3
        f3 s = ld3(pr + 5);            // w5 w6 w7
        float wi[9];
        ld9(pi, wi);

        // pre-reduce this feature to the 9 floats E consumes
        float p0 = q.x - q.z;          // re01
        float p1 = q.y - s.y;          // re02
        float p2 = s.x - s.z;          // re12
        float p3 = wi[1] + wi[3];      // si01
        float p4 = wi[2] + wi[6];      // si02
        float p5 = wi[5] + wi[7];      // si12
        float p6 = wi[0], p7 = wi[4], p8 = wi[8];

        // ahw[mu*8+f]: address uniform across lanes -> scalar loads (SGPR),
        // SGPR x VGPR fma, zero VGPR cost for the weights.
        const float w0 = ahw[0 * 8 + f], w1 = ahw[1 * 8 + f];
        const float w2 = ahw[2 * 8 + f], w3 = ahw[3 * 8 + f];
        acc0[0]=fmaf(w0,p0,acc0[0]); acc0[1]=fmaf(w0,p1,acc0[1]); acc0[2]=fmaf(w0,p2,acc0[2]);
        acc0[3]=fmaf(w0,p3,acc0[3]); acc0[4]=fmaf(w0,p4,acc0[4]); acc0[5]=fmaf(w0,p5,acc0[5]);
        acc0[6]=fmaf(w0,p6,acc0[6]); acc0[7]=fmaf(w0,p7,acc0[7]); acc0[8]=fmaf(w0,p8,acc0[8]);
        acc1[0]=fmaf(w1,p0,acc1[0]); acc1[1]=fmaf(w1,p1,acc1[1]); acc1[2]=fmaf(w1,p2,acc1[2]);
        acc1[3]=fmaf(w1,p3,acc1[3]); acc1[4]=fmaf(w1,p4,acc1[4]); acc1[5]=fmaf(w1,p5,acc1[5]);
        acc1[6]=fmaf(w1,p6,acc1[6]); acc1[7]=fmaf(w1,p7,acc1[7]); acc1[8]=fmaf(w1,p8,acc1[8]);
        acc2[0]=fmaf(w2,p0,acc2[0]); acc2[1]=fmaf(w2,p1,acc2[1]); acc2[2]=fmaf(w2,p2,acc2[2]);
        acc2[3]=fmaf(w2,p3,acc2[3]); acc2[4]=fmaf(w2,p4,acc2[4]); acc2[5]=fmaf(w2,p5,acc2[5]);
        acc2[6]=fmaf(w2,p6,acc2[6]); acc2[7]=fmaf(w2,p7,acc2[7]); acc2[8]=fmaf(w2,p8,acc2[8]);
        acc3[0]=fmaf(w3,p0,acc3[0]); acc3[1]=fmaf(w3,p1,acc3[1]); acc3[2]=fmaf(w3,p2,acc3[2]);
        acc3[3]=fmaf(w3,p3,acc3[3]); acc3[4]=fmaf(w3,p4,acc3[4]); acc3[5]=fmaf(w3,p5,acc3[5]);
        acc3[6]=fmaf(w3,p6,acc3[6]); acc3[7]=fmaf(w3,p7,acc3[7]); acc3[8]=fmaf(w3,p8,acc3[8]);
    }

    // ---- four sequential expm+apply phases, registers reused across phases;
    //      each phase's U load issues first and flies under its expm.
    const float* accs[4] = { acc0, acc1, acc2, acc3 };
    #pragma unroll
    for (int mu = 0; mu < 4; mu++) {
        const size_t ub = ((size_t)mu * NSITES + site) * 9;
        float ur[9], ui[9];
        ld9(U_re + ub, ur);
        ld9(U_im + ub, ui);
        const Edof E = make_edof(accs[mu]);
        cplx g0, g1, g2;
        expm_coeffs(E, g0, g1, g2);
        apply_store(E, g0, g1, g2, ur, ui, out + ub);
    }
}

extern "C" void kernel_launch(void* const* d_in, const int* in_sizes, int n_in,
                              void* d_out, int out_size, void* d_ws, size_t ws_size,
                              hipStream_t stream) {
    const float* U_re = (const float*)d_in[0];
    const float* U_im = (const float*)d_in[1];
    const float* W_re = (const float*)d_in[2];
    const float* W_im = (const float*)d_in[3];
    const float* ahw  = (const float*)d_in[4];
    float* out = (float*)d_out;
    // one lane per SITE (all 4 mu per lane): 131072 lanes = 512 blocks x 256
    lge_exp_kernel<<<dim3(NSITES / 256), dim3(256), 0, stream>>>(
        U_re, U_im, W_re, W_im, ahw, out);
}

// Round 10
// 165.061 us; speedup vs baseline: 1.0584x; 1.0584x over previous
//
#include <hip/hip_runtime.h>
#include <math.h>

#define NSITES 131072      // 32*16*16*16
#define PL     (NSITES * 9)   // floats per feature plane

struct cplx { float re, im; };

__device__ __forceinline__ cplx cadd(cplx a, cplx b) { return {a.re + b.re, a.im + b.im}; }
__device__ __forceinline__ cplx cmul(cplx a, cplx b) {
    return { fmaf(a.re, b.re, -(a.im * b.im)), fmaf(a.re, b.im, a.im * b.re) };
}

// 12-byte vector load (global_load_dwordx3); rows are 36 B so only 4B-aligned
struct __attribute__((aligned(4))) f3 { float x, y, z; };
__device__ __forceinline__ f3 ld3(const float* __restrict__ p) { return *(const f3*)p; }

// NAMED-FIELD accumulator: no arrays, no pointers -> never addressable,
// never demoted to scratch (R9's accs[4] pointer array stack-allocated the
// accumulators: 45 MB scratch each way, 68 us).
struct Acc9 { float r01, r02, r12, i01, i02, i12, d0, d4, d8; };

// 8-DOF anti-hermitian traceless E (same fields after trace projection)
struct Edof { float er01, er02, er12, ei01, ei02, ei12, ed0, ed1, ed2; };

__device__ __forceinline__ Edof make_edof(const Acc9& a) {
    Edof E;
    E.er01 = a.r01; E.er02 = a.r02; E.er12 = a.r12;
    E.ei01 = a.i01; E.ei02 = a.i02; E.ei12 = a.i12;
    float t3 = (a.d0 + a.d4 + a.d8) * (2.f / 3.f);
    E.ed0 = fmaf(2.f, a.d0, -t3);
    E.ed1 = fmaf(2.f, a.d4, -t3);
    E.ed2 = fmaf(2.f, a.d8, -t3);     // == -ed0-ed1
    return E;
}

// exp(E) = g0 I + g1 E + g2 E^2 via Cayley-Hamilton (p real, q imaginary),
// scaling from exponent bits of ||E||_F^2, Taylor(10) + repeated squaring.
__device__ __forceinline__ void expm_coeffs(const Edof& E, cplx& g0o, cplx& g1o, cplx& g2o)
{
    float r2 = fmaf(E.er01, E.er01, fmaf(E.er02, E.er02, fmaf(E.er12, E.er12,
               fmaf(E.ei01, E.ei01, fmaf(E.ei02, E.ei02, E.ei12 * E.ei12)))));
    r2 = fmaf(2.f, r2, fmaf(E.ed0, E.ed0, fmaf(E.ed1, E.ed1, E.ed2 * E.ed2)));

    const float n01 = fmaf(E.ei01, E.ei01, E.er01 * E.er01);
    const float n02 = fmaf(E.ei02, E.ei02, E.er02 * E.er02);
    const float n12 = fmaf(E.ei12, E.ei12, E.er12 * E.er12);
    const float zre = fmaf(E.ei01, E.ei12, -(E.er01 * E.er12));
    const float zim = -fmaf(E.ei01, E.er12, E.er01 * E.ei12);
    const float detH = E.ed0 * E.ed1 * E.ed2
                     + 2.f * fmaf(zre, E.ei02, -(zim * E.er02))
                     - fmaf(E.ed0, n12, fmaf(E.ed1, n02, E.ed2 * n01));

    int e; (void)frexpf(r2, &e);                 // r2 = m*2^e, m in [0.5,1)
    int sc = (e <= -2) ? 0 : min(1 + ((e + 1) >> 1), 40);
    const float inv  = __int_as_float((127 - sc) << 23);   // 2^-sc
    const float inv2 = inv * inv;
    const float px   = -0.5f * r2 * inv2;        // p of scaled X (real)
    const float qxi  = -detH * (inv2 * inv);     // q of scaled X = i*qxi

    cplx T0 = {1.f, 0.f}, T1 = {0.f, 0.f}, T2 = {0.f, 0.f};
    cplx S0 = {1.f, 0.f}, S1 = {0.f, 0.f}, S2 = {0.f, 0.f};
    #pragma unroll
    for (int n = 1; n <= 10; n++) {
        float c  = 1.f / (float)n;               // folds to a literal
        float qc = qxi * c;
        cplx nT0 = { -qc * T2.im, qc * T2.re };
        cplx nT1 = { c * fmaf(px, T2.re, T0.re), c * fmaf(px, T2.im, T0.im) };
        cplx nT2 = { c * T1.re, c * T1.im };
        T0 = nT0; T1 = nT1; T2 = nT2;
        S0 = cadd(S0, T0); S1 = cadd(S1, T1); S2 = cadd(S2, T2);
    }

    const float q2 = 2.f * qxi;
    for (int k = 0; k < sc; k++) {
        cplx f0 = S0, f1 = S1, f2 = S2;
        cplx f12 = cmul(f1, f2);
        cplx f01 = cmul(f0, f1);
        cplx f02 = cmul(f0, f2);
        float f00re = fmaf(f0.re, f0.re, -(f0.im * f0.im)), f00im = 2.f * f0.re * f0.im;
        float f11re = fmaf(f1.re, f1.re, -(f1.im * f1.im)), f11im = 2.f * f1.re * f1.im;
        float f22re = fmaf(f2.re, f2.re, -(f2.im * f2.im)), f22im = 2.f * f2.re * f2.im;
        S0.re = fmaf(-q2, f12.im, f00re);
        S0.im = fmaf( q2, f12.re, f00im);
        S1.re = fmaf(-qxi, f22im, 2.f * fmaf(px, f12.re, f01.re));
        S1.im = fmaf( qxi, f22re, 2.f * fmaf(px, f12.im, f01.im));
        S2.re = fmaf(px, f22re, fmaf(2.f, f02.re, f11re));
        S2.im = fmaf(px, f22im, fmaf(2.f, f02.im, f11im));
    }
    g0o = S0;
    g1o = { S1.re * inv,  S1.im * inv  };
    g2o = { S2.re * inv2, S2.im * inv2 };
}

__device__ __forceinline__ void ecol(const Edof& E, cplx m0, cplx m1, cplx m2,
                                     cplx& v0, cplx& v1, cplx& v2)
{
    v0.re = fmaf(-E.ed0, m0.im, fmaf(E.er01, m1.re, fmaf(-E.ei01, m1.im, fmaf(E.er02, m2.re, -(E.ei02 * m2.im)))));
    v0.im = fmaf( E.ed0, m0.re, fmaf(E.er01, m1.im, fmaf( E.ei01, m1.re, fmaf(E.er02, m2.im,  (E.ei02 * m2.re)))));
    v1.re = fmaf(-E.er01, m0.re, fmaf(-E.ei01, m0.im, fmaf(-E.ed1, m1.im, fmaf(E.er12, m2.re, -(E.ei12 * m2.im)))));
    v1.im = fmaf(-E.er01, m0.im, fmaf( E.ei01, m0.re, fmaf( E.ed1, m1.re, fmaf(E.er12, m2.im,  (E.ei12 * m2.re)))));
    v2.re = fmaf(-E.er02, m0.re, fmaf(-E.ei02, m0.im, fmaf(-E.er12, m1.re, fmaf(-E.ei12, m1.im, -(E.ed2 * m2.im)))));
    v2.im = fmaf(-E.er02, m0.im, fmaf( E.ei02, m0.re, fmaf(-E.er12, m1.im, fmaf( E.ei12, m1.re,  (E.ed2 * m2.re)))));
}

__device__ __forceinline__ float ocomb(cplx g0, cplx g1, cplx g2, cplx m, cplx v, cplx z) {
    return fmaf(g0.re, m.re, fmaf(-g0.im, m.im, fmaf(g1.re, v.re, fmaf(-g1.im, v.im,
           fmaf(g2.re, z.re, -(g2.im * z.im))))));
}

// one full mu-phase: U load -> expm -> apply -> store. All values named;
// registers recycled across the 4 sequential calls.
__device__ __forceinline__ void phase(const Acc9& acc,
                                      const float* __restrict__ U_re,
                                      const float* __restrict__ U_im,
                                      float* __restrict__ out, size_t ub)
{
    f3 ua = ld3(U_re + ub), ubv = ld3(U_re + ub + 3), uc = ld3(U_re + ub + 6);
    f3 va = ld3(U_im + ub), vb  = ld3(U_im + ub + 3), vc = ld3(U_im + ub + 6);

    const Edof E = make_edof(acc);
    cplx g0, g1, g2;
    expm_coeffs(E, g0, g1, g2);     // U loads in flight under this

    const float ur0=ua.x, ur1=ua.y, ur2=ua.z, ur3=ubv.x, ur4=ubv.y, ur5=ubv.z,
                ur6=uc.x, ur7=uc.y, ur8=uc.z;
    const float ui0=va.x, ui1=va.y, ui2=va.z, ui3=vb.x,  ui4=vb.y,  ui5=vb.z,
                ui6=vc.x, ui7=vc.y, ui8=vc.z;

    float o0,o1,o2,o3,o4,o5,o6,o7,o8;
    {
        cplx m0={ur0,ui0}, m1={ur3,ui3}, m2={ur6,ui6};
        cplx v0,v1,v2,z0,z1,z2;
        ecol(E,m0,m1,m2,v0,v1,v2); ecol(E,v0,v1,v2,z0,z1,z2);
        o0=ocomb(g0,g1,g2,m0,v0,z0); o3=ocomb(g0,g1,g2,m1,v1,z1); o6=ocomb(g0,g1,g2,m2,v2,z2);
    }
    {
        cplx m0={ur1,ui1}, m1={ur4,ui4}, m2={ur7,ui7};
        cplx v0,v1,v2,z0,z1,z2;
        ecol(E,m0,m1,m2,v0,v1,v2); ecol(E,v0,v1,v2,z0,z1,z2);
        o1=ocomb(g0,g1,g2,m0,v0,z0); o4=ocomb(g0,g1,g2,m1,v1,z1); o7=ocomb(g0,g1,g2,m2,v2,z2);
    }
    {
        cplx m0={ur2,ui2}, m1={ur5,ui5}, m2={ur8,ui8};
        cplx v0,v1,v2,z0,z1,z2;
        ecol(E,m0,m1,m2,v0,v1,v2); ecol(E,v0,v1,v2,z0,z1,z2);
        o2=ocomb(g0,g1,g2,m0,v0,z0); o5=ocomb(g0,g1,g2,m1,v1,z1); o8=ocomb(g0,g1,g2,m2,v2,z2);
    }
    float* ob = out + ub;
    *(f3*)(ob)     = { o0, o1, o2 };
    *(f3*)(ob + 3) = { o3, o4, o5 };
    *(f3*)(ob + 6) = { o6, o7, o8 };
}

// ONE LANE = ONE SITE, ALL 4 MU (lane-byte ceiling model, R8 post-mortem):
// vector memory path services ~6.5 TB/s of LANE-level bytes (duplicates
// included); R4/R8 serviced ~308 MB -> 45 us AT that ceiling. W loaded once
// per site (480 B), pre-reduced, accumulated into four E's with FULLY UNIFORM
// ahw weights (SGPR x VGPR fma, zero redistribution). Serviced: ~120 MB.
// R9 proved the structure but poisoned codegen via a pointer array
// (accs[4] -> stack demotion -> 45 MB scratch each way). This version:
// named struct fields only, hand-unrolled phases, nothing addressable.
//
// launch_bounds NOTE (measured): (256,8) 64-VGPR cap -> 155 MB spill;
// (256,6) pressure mode -> 48.7 MB spill; (256,4) = 128-reg budget, clean in
// R0/R3/R4/R5/R8. Needs ~70-100 VGPR: WRITE_SIZE must stay 18.5 MB.
__global__ __launch_bounds__(256, 4) void lge_exp_kernel(
    const float* __restrict__ U_re, const float* __restrict__ U_im,
    const float* __restrict__ W_re, const float* __restrict__ W_im,
    const float* __restrict__ ahw,  float* __restrict__ out)
{
    const int site = blockIdx.x * 256 + threadIdx.x;   // 0..131071
    const size_t sb = (size_t)site * 9;

    Acc9 A0 = {0,0,0,0,0,0,0,0,0};
    Acc9 A1 = {0,0,0,0,0,0,0,0,0};
    Acc9 A2 = {0,0,0,0,0,0,0,0,0};
    Acc9 A3 = {0,0,0,0,0,0,0,0,0};

    #pragma unroll
    for (int f = 0; f < 8; f++) {
        const float* pr = W_re + (size_t)f * PL + sb;
        const float* pi = W_im + (size_t)f * PL + sb;
        f3 q  = ld3(pr + 1);           // w1 w2 w3
        f3 s  = ld3(pr + 5);           // w5 w6 w7
        f3 ia = ld3(pi), ib = ld3(pi + 3), ic = ld3(pi + 6);

        // pre-reduce this feature to the 9 floats E consumes (named scalars)
        const float p0 = q.x - q.z;          // re01
        const float p1 = q.y - s.y;          // re02
        const float p2 = s.x - s.z;          // re12
        const float p3 = ia.y + ib.x;        // si01 = wi1 + wi3
        const float p4 = ia.z + ic.x;        // si02 = wi2 + wi6
        const float p5 = ib.z + ic.y;        // si12 = wi5 + wi7
        const float p6 = ia.x, p7 = ib.y, p8 = ic.z;   // wi0, wi4, wi8

        // ahw[mu*8+f]: uniform address -> scalar (SGPR) operand, f is
        // compile-time after unroll.
        const float w0 = ahw[0 * 8 + f], w1 = ahw[1 * 8 + f];
        const float w2 = ahw[2 * 8 + f], w3 = ahw[3 * 8 + f];

        A0.r01=fmaf(w0,p0,A0.r01); A0.r02=fmaf(w0,p1,A0.r02); A0.r12=fmaf(w0,p2,A0.r12);
        A0.i01=fmaf(w0,p3,A0.i01); A0.i02=fmaf(w0,p4,A0.i02); A0.i12=fmaf(w0,p5,A0.i12);
        A0.d0 =fmaf(w0,p6,A0.d0);  A0.d4 =fmaf(w0,p7,A0.d4);  A0.d8 =fmaf(w0,p8,A0.d8);

        A1.r01=fmaf(w1,p0,A1.r01); A1.r02=fmaf(w1,p1,A1.r02); A1.r12=fmaf(w1,p2,A1.r12);
        A1.i01=fmaf(w1,p3,A1.i01); A1.i02=fmaf(w1,p4,A1.i02); A1.i12=fmaf(w1,p5,A1.i12);
        A1.d0 =fmaf(w1,p6,A1.d0);  A1.d4 =fmaf(w1,p7,A1.d4);  A1.d8 =fmaf(w1,p8,A1.d8);

        A2.r01=fmaf(w2,p0,A2.r01); A2.r02=fmaf(w2,p1,A2.r02); A2.r12=fmaf(w2,p2,A2.r12);
        A2.i01=fmaf(w2,p3,A2.i01); A2.i02=fmaf(w2,p4,A2.i02); A2.i12=fmaf(w2,p5,A2.i12);
        A2.d0 =fmaf(w2,p6,A2.d0);  A2.d4 =fmaf(w2,p7,A2.d4);  A2.d8 =fmaf(w2,p8,A2.d8);

        A3.r01=fmaf(w3,p0,A3.r01); A3.r02=fmaf(w3,p1,A3.r02); A3.r12=fmaf(w3,p2,A3.r12);
        A3.i01=fmaf(w3,p3,A3.i01); A3.i02=fmaf(w3,p4,A3.i02); A3.i12=fmaf(w3,p5,A3.i12);
        A3.d0 =fmaf(w3,p6,A3.d0);  A3.d4 =fmaf(w3,p7,A3.d4);  A3.d8 =fmaf(w3,p8,A3.d8);
    }

    // ---- four hand-unrolled phases; each releases its registers to the next
    phase(A0, U_re, U_im, out, ((size_t)0 * NSITES + site) * 9);
    phase(A1, U_re, U_im, out, ((size_t)1 * NSITES + site) * 9);
    phase(A2, U_re, U_im, out, ((size_t)2 * NSITES + site) * 9);
    phase(A3, U_re, U_im, out, ((size_t)3 * NSITES + site) * 9);
}

extern "C" void kernel_launch(void* const* d_in, const int* in_sizes, int n_in,
                              void* d_out, int out_size, void* d_ws, size_t ws_size,
                              hipStream_t stream) {
    const float* U_re = (const float*)d_in[0];
    const float* U_im = (const float*)d_in[1];
    const float* W_re = (const float*)d_in[2];
    const float* W_im = (const float*)d_in[3];
    const float* ahw  = (const float*)d_in[4];
    float* out = (float*)d_out;
    // one lane per SITE (all 4 mu per lane): 131072 lanes = 512 blocks x 256
    lge_exp_kernel<<<dim3(NSITES / 256), dim3(256), 0, stream>>>(
        U_re, U_im, W_re, W_im, ahw, out);
}

// Round 11
// 143.903 us; speedup vs baseline: 1.2141x; 1.1470x over previous
//
#include <hip/hip_runtime.h>
#include <math.h>

#define NSITES 131072      // 32*16*16*16
#define PL     (NSITES * 9)   // floats per feature plane

struct cplx { float re, im; };

__device__ __forceinline__ cplx cadd(cplx a, cplx b) { return {a.re + b.re, a.im + b.im}; }
__device__ __forceinline__ cplx cmul(cplx a, cplx b) {
    return { fmaf(a.re, b.re, -(a.im * b.im)), fmaf(a.re, b.im, a.im * b.re) };
}

// 12-byte vector load (global_load_dwordx3); rows are 36 B so only 4B-aligned
struct __attribute__((aligned(4))) f3 { float x, y, z; };
__device__ __forceinline__ f3 ld3(const float* __restrict__ p) { return *(const f3*)p; }

// Named-field accumulator. Everything below is BY VALUE / RETURN BY VALUE:
// R9 (pointer array) and R10 (by-reference params / out-params) both left
// addressable locals -> stack demotion -> 27-45 MB scratch traffic each way.
struct Acc9 { float r01, r02, r12, i01, i02, i12, d0, d4, d8; };
struct Edof { float er01, er02, er12, ei01, ei02, ei12, ed0, ed1, ed2; };
struct G3   { cplx g0, g1, g2; };
struct C3   { cplx c0, c1, c2; };

__device__ __forceinline__ Edof make_edof(Acc9 a) {
    Edof E;
    E.er01 = a.r01; E.er02 = a.r02; E.er12 = a.r12;
    E.ei01 = a.i01; E.ei02 = a.i02; E.ei12 = a.i12;
    float t3 = (a.d0 + a.d4 + a.d8) * (2.f / 3.f);
    E.ed0 = fmaf(2.f, a.d0, -t3);
    E.ed1 = fmaf(2.f, a.d4, -t3);
    E.ed2 = fmaf(2.f, a.d8, -t3);     // == -ed0-ed1
    return E;
}

// exp(E) = g0 I + g1 E + g2 E^2 via Cayley-Hamilton (p real, q imaginary),
// scaling from exponent bits of ||E||_F^2, Taylor(10) + repeated squaring.
__device__ __forceinline__ G3 expm_coeffs(Edof E)
{
    float r2 = fmaf(E.er01, E.er01, fmaf(E.er02, E.er02, fmaf(E.er12, E.er12,
               fmaf(E.ei01, E.ei01, fmaf(E.ei02, E.ei02, E.ei12 * E.ei12)))));
    r2 = fmaf(2.f, r2, fmaf(E.ed0, E.ed0, fmaf(E.ed1, E.ed1, E.ed2 * E.ed2)));

    const float n01 = fmaf(E.ei01, E.ei01, E.er01 * E.er01);
    const float n02 = fmaf(E.ei02, E.ei02, E.er02 * E.er02);
    const float n12 = fmaf(E.ei12, E.ei12, E.er12 * E.er12);
    const float zre = fmaf(E.ei01, E.ei12, -(E.er01 * E.er12));
    const float zim = -fmaf(E.ei01, E.er12, E.er01 * E.ei12);
    const float detH = E.ed0 * E.ed1 * E.ed2
                     + 2.f * fmaf(zre, E.ei02, -(zim * E.er02))
                     - fmaf(E.ed0, n12, fmaf(E.ed1, n02, E.ed2 * n01));

    int e; (void)frexpf(r2, &e);                 // r2 = m*2^e, m in [0.5,1)
    int sc = (e <= -2) ? 0 : min(1 + ((e + 1) >> 1), 40);
    const float inv  = __int_as_float((127 - sc) << 23);   // 2^-sc
    const float inv2 = inv * inv;
    const float px   = -0.5f * r2 * inv2;        // p of scaled X (real)
    const float qxi  = -detH * (inv2 * inv);     // q of scaled X = i*qxi

    cplx T0 = {1.f, 0.f}, T1 = {0.f, 0.f}, T2 = {0.f, 0.f};
    cplx S0 = {1.f, 0.f}, S1 = {0.f, 0.f}, S2 = {0.f, 0.f};
    #pragma unroll
    for (int n = 1; n <= 10; n++) {
        float c  = 1.f / (float)n;               // folds to a literal
        float qc = qxi * c;
        cplx nT0 = { -qc * T2.im, qc * T2.re };
        cplx nT1 = { c * fmaf(px, T2.re, T0.re), c * fmaf(px, T2.im, T0.im) };
        cplx nT2 = { c * T1.re, c * T1.im };
        T0 = nT0; T1 = nT1; T2 = nT2;
        S0 = cadd(S0, T0); S1 = cadd(S1, T1); S2 = cadd(S2, T2);
    }

    const float q2 = 2.f * qxi;
    for (int k = 0; k < sc; k++) {
        cplx f0 = S0, f1 = S1, f2 = S2;
        cplx f12 = cmul(f1, f2);
        cplx f01 = cmul(f0, f1);
        cplx f02 = cmul(f0, f2);
        float f00re = fmaf(f0.re, f0.re, -(f0.im * f0.im)), f00im = 2.f * f0.re * f0.im;
        float f11re = fmaf(f1.re, f1.re, -(f1.im * f1.im)), f11im = 2.f * f1.re * f1.im;
        float f22re = fmaf(f2.re, f2.re, -(f2.im * f2.im)), f22im = 2.f * f2.re * f2.im;
        S0.re = fmaf(-q2, f12.im, f00re);
        S0.im = fmaf( q2, f12.re, f00im);
        S1.re = fmaf(-qxi, f22im, 2.f * fmaf(px, f12.re, f01.re));
        S1.im = fmaf( qxi, f22re, 2.f * fmaf(px, f12.im, f01.im));
        S2.re = fmaf(px, f22re, fmaf(2.f, f02.re, f11re));
        S2.im = fmaf(px, f22im, fmaf(2.f, f02.im, f11im));
    }
    G3 g;
    g.g0 = S0;
    g.g1 = { S1.re * inv,  S1.im * inv  };
    g.g2 = { S2.re * inv2, S2.im * inv2 };
    return g;
}

__device__ __forceinline__ C3 ecol(Edof E, C3 m)
{
    C3 v;
    v.c0.re = fmaf(-E.ed0, m.c0.im, fmaf(E.er01, m.c1.re, fmaf(-E.ei01, m.c1.im, fmaf(E.er02, m.c2.re, -(E.ei02 * m.c2.im)))));
    v.c0.im = fmaf( E.ed0, m.c0.re, fmaf(E.er01, m.c1.im, fmaf( E.ei01, m.c1.re, fmaf(E.er02, m.c2.im,  (E.ei02 * m.c2.re)))));
    v.c1.re = fmaf(-E.er01, m.c0.re, fmaf(-E.ei01, m.c0.im, fmaf(-E.ed1, m.c1.im, fmaf(E.er12, m.c2.re, -(E.ei12 * m.c2.im)))));
    v.c1.im = fmaf(-E.er01, m.c0.im, fmaf( E.ei01, m.c0.re, fmaf( E.ed1, m.c1.re, fmaf(E.er12, m.c2.im,  (E.ei12 * m.c2.re)))));
    v.c2.re = fmaf(-E.er02, m.c0.re, fmaf(-E.ei02, m.c0.im, fmaf(-E.er12, m.c1.re, fmaf(-E.ei12, m.c1.im, -(E.ed2 * m.c2.im)))));
    v.c2.im = fmaf(-E.er02, m.c0.im, fmaf( E.ei02, m.c0.re, fmaf(-E.er12, m.c1.im, fmaf( E.ei12, m.c1.re,  (E.ed2 * m.c2.re)))));
    return v;
}

__device__ __forceinline__ float ocomb(G3 g, cplx m, cplx v, cplx z) {
    return fmaf(g.g0.re, m.re, fmaf(-g.g0.im, m.im, fmaf(g.g1.re, v.re, fmaf(-g.g1.im, v.im,
           fmaf(g.g2.re, z.re, -(g.g2.im * z.im))))));
}

// one full mu-phase. U loads issue AFTER expm (no multi-phase prefetch live
// range); caller places sched_barrier(0) between phases so the scheduler
// cannot hoist all four phases' U loads into flight at once (R10's spill).
__device__ __forceinline__ void phase(Acc9 acc,
                                      const float* __restrict__ U_re,
                                      const float* __restrict__ U_im,
                                      float* __restrict__ out, size_t ub)
{
    Edof E = make_edof(acc);
    G3 g = expm_coeffs(E);

    f3 ua = ld3(U_re + ub), ubv = ld3(U_re + ub + 3), uc = ld3(U_re + ub + 6);
    f3 va = ld3(U_im + ub), vb  = ld3(U_im + ub + 3), vc = ld3(U_im + ub + 6);

    float o0,o1,o2,o3,o4,o5,o6,o7,o8;
    {   // column 0: U elements 0,3,6
        C3 m = { cplx{ua.x, va.x}, cplx{ubv.x, vb.x}, cplx{uc.x, vc.x} };
        C3 v = ecol(E, m);
        C3 z = ecol(E, v);
        o0 = ocomb(g, m.c0, v.c0, z.c0);
        o3 = ocomb(g, m.c1, v.c1, z.c1);
        o6 = ocomb(g, m.c2, v.c2, z.c2);
    }
    {   // column 1: U elements 1,4,7
        C3 m = { cplx{ua.y, va.y}, cplx{ubv.y, vb.y}, cplx{uc.y, vc.y} };
        C3 v = ecol(E, m);
        C3 z = ecol(E, v);
        o1 = ocomb(g, m.c0, v.c0, z.c0);
        o4 = ocomb(g, m.c1, v.c1, z.c1);
        o7 = ocomb(g, m.c2, v.c2, z.c2);
    }
    {   // column 2: U elements 2,5,8
        C3 m = { cplx{ua.z, va.z}, cplx{ubv.z, vb.z}, cplx{uc.z, vc.z} };
        C3 v = ecol(E, m);
        C3 z = ecol(E, v);
        o2 = ocomb(g, m.c0, v.c0, z.c0);
        o5 = ocomb(g, m.c1, v.c1, z.c1);
        o8 = ocomb(g, m.c2, v.c2, z.c2);
    }
    float* ob = out + ub;
    *(f3*)(ob)     = { o0, o1, o2 };
    *(f3*)(ob + 3) = { o3, o4, o5 };
    *(f3*)(ob + 6) = { o6, o7, o8 };
}

// ONE LANE = ONE SITE, ALL 4 MU (lane-byte ceiling model): the vector memory
// path services ~6.5 TB/s of LANE-level bytes; R4/R8 serviced ~308 MB (4x
// duplicated W) -> 45 us AT the ceiling. Here W is loaded once per site
// (480 B), pre-reduced, accumulated into four E's with FULLY UNIFORM ahw
// weights (SGPR operands, zero redistribution). Serviced: ~120 MB -> ~19 us
// floor. R9/R10 proved the structure but spilled (45/27 MB scratch).
//
// KEY ALLOCATOR FACT (R0-R10): hipcc NEVER allocated >64 VGPRs in any round
// -- its occupancy heuristic targets the 8-waves/EU tier and spills instead.
// At THIS grid (512 blocks = 2 blocks/CU = 2 waves/SIMD) occupancy is
// grid-capped at 2 waves/EU, so regs are free up to 256.
// amdgpu_waves_per_eu(2,2) tells the allocator exactly that.
__global__
__attribute__((amdgpu_flat_work_group_size(256, 256)))
__attribute__((amdgpu_waves_per_eu(2, 2)))
void lge_exp_kernel(
    const float* __restrict__ U_re, const float* __restrict__ U_im,
    const float* __restrict__ W_re, const float* __restrict__ W_im,
    const float* __restrict__ ahw,  float* __restrict__ out)
{
    const int site = blockIdx.x * 256 + threadIdx.x;   // 0..131071
    const size_t sb = (size_t)site * 9;

    Acc9 A0 = {0,0,0,0,0,0,0,0,0};
    Acc9 A1 = {0,0,0,0,0,0,0,0,0};
    Acc9 A2 = {0,0,0,0,0,0,0,0,0};
    Acc9 A3 = {0,0,0,0,0,0,0,0,0};

    #pragma unroll
    for (int f = 0; f < 8; f++) {
        const float* pr = W_re + (size_t)f * PL + sb;
        const float* pi = W_im + (size_t)f * PL + sb;
        f3 q  = ld3(pr + 1);           // w1 w2 w3
        f3 s  = ld3(pr + 5);           // w5 w6 w7
        f3 ia = ld3(pi), ib = ld3(pi + 3), ic = ld3(pi + 6);

        // pre-reduce this feature to the 9 floats E consumes (named scalars)
        const float p0 = q.x - q.z;          // re01
        const float p1 = q.y - s.y;          // re02
        const float p2 = s.x - s.z;          // re12
        const float p3 = ia.y + ib.x;        // si01 = wi1 + wi3
        const float p4 = ia.z + ic.x;        // si02 = wi2 + wi6
        const float p5 = ib.z + ic.y;        // si12 = wi5 + wi7
        const float p6 = ia.x, p7 = ib.y, p8 = ic.z;   // wi0, wi4, wi8

        // ahw[mu*8+f]: uniform address, f compile-time -> s_load, SGPR x VGPR fma
        const float w0 = ahw[0 * 8 + f], w1 = ahw[1 * 8 + f];
        const float w2 = ahw[2 * 8 + f], w3 = ahw[3 * 8 + f];

        A0.r01=fmaf(w0,p0,A0.r01); A0.r02=fmaf(w0,p1,A0.r02); A0.r12=fmaf(w0,p2,A0.r12);
        A0.i01=fmaf(w0,p3,A0.i01); A0.i02=fmaf(w0,p4,A0.i02); A0.i12=fmaf(w0,p5,A0.i12);
        A0.d0 =fmaf(w0,p6,A0.d0);  A0.d4 =fmaf(w0,p7,A0.d4);  A0.d8 =fmaf(w0,p8,A0.d8);

        A1.r01=fmaf(w1,p0,A1.r01); A1.r02=fmaf(w1,p1,A1.r02); A1.r12=fmaf(w1,p2,A1.r12);
        A1.i01=fmaf(w1,p3,A1.i01); A1.i02=fmaf(w1,p4,A1.i02); A1.i12=fmaf(w1,p5,A1.i12);
        A1.d0 =fmaf(w1,p6,A1.d0);  A1.d4 =fmaf(w1,p7,A1.d4);  A1.d8 =fmaf(w1,p8,A1.d8);

        A2.r01=fmaf(w2,p0,A2.r01); A2.r02=fmaf(w2,p1,A2.r02); A2.r12=fmaf(w2,p2,A2.r12);
        A2.i01=fmaf(w2,p3,A2.i01); A2.i02=fmaf(w2,p4,A2.i02); A2.i12=fmaf(w2,p5,A2.i12);
        A2.d0 =fmaf(w2,p6,A2.d0);  A2.d4 =fmaf(w2,p7,A2.d4);  A2.d8 =fmaf(w2,p8,A2.d8);

        A3.r01=fmaf(w3,p0,A3.r01); A3.r02=fmaf(w3,p1,A3.r02); A3.r12=fmaf(w3,p2,A3.r12);
        A3.i01=fmaf(w3,p3,A3.i01); A3.i02=fmaf(w3,p4,A3.i02); A3.i12=fmaf(w3,p5,A3.i12);
        A3.d0 =fmaf(w3,p6,A3.d0);  A3.d4 =fmaf(w3,p7,A3.d4);  A3.d8 =fmaf(w3,p8,A3.d8);
    }

    // four phases; sched_barrier(0) stops cross-phase load hoisting
    phase(A0, U_re, U_im, out, ((size_t)0 * NSITES + site) * 9);
    __builtin_amdgcn_sched_barrier(0);
    phase(A1, U_re, U_im, out, ((size_t)1 * NSITES + site) * 9);
    __builtin_amdgcn_sched_barrier(0);
    phase(A2, U_re, U_im, out, ((size_t)2 * NSITES + site) * 9);
    __builtin_amdgcn_sched_barrier(0);
    phase(A3, U_re, U_im, out, ((size_t)3 * NSITES + site) * 9);
}

extern "C" void kernel_launch(void* const* d_in, const int* in_sizes, int n_in,
                              void* d_out, int out_size, void* d_ws, size_t ws_size,
                              hipStream_t stream) {
    const float* U_re = (const float*)d_in[0];
    const float* U_im = (const float*)d_in[1];
    const float* W_re = (const float*)d_in[2];
    const float* W_im = (const float*)d_in[3];
    const float* ahw  = (const float*)d_in[4];
    float* out = (float*)d_out;
    // one lane per SITE (all 4 mu per lane): 131072 lanes = 512 blocks x 256
    lge_exp_kernel<<<dim3(NSITES / 256), dim3(256), 0, stream>>>(
        U_re, U_im, W_re, W_im, ahw, out);
}